// Round 1
// baseline (246.908 us; speedup 1.0000x reference)
//
#include <hip/hip_runtime.h>

// Octree cross-entropy loss.
// D=256, BS=16 -> 4096 level-0 blocks of 16^3 voxels.
// Level 0: per-voxel 2-class CE, mean over block, summed over blocks.
// Levels 1..4 (b = 32,64,128,256): 3-class CE (pure0/pure1/mixed) * b^3,
// class derived from per-16^3-block popcounts of gt01 aggregated upward.
//
// R3 -> R4 changes:
//  - level0: 256-thread blocks, 16 voxels/thread => 12 independent 16-B loads
//    per thread (4x int4 gt + 8x float4 logits) all issued before any use.
//    R3's __launch_bounds__(1024) squeezed the kernel to 16 VGPRs, which
//    serialized the loads (counters: 20% HBM BW, 18% VALUBusy, latency-bound).
//    __launch_bounds__(256,4) lets the allocator keep all 48 destination
//    VGPRs live (cap 128 VGPR, >=16 waves/CU) -> ~12 KB in flight per wave.

__device__ __forceinline__ float softplus(float x) {
    // log(1 + e^x), stable
    return fmaxf(x, 0.f) + __logf(1.f + __expf(-fabsf(x)));
}

__device__ __forceinline__ float nll3(const float* __restrict__ l, int c) {
    float a = l[0], b = l[1], d = l[2];
    float m = fmaxf(fmaxf(a, b), d);
    float lse = m + __logf(__expf(a - m) + __expf(b - m) + __expf(d - m));
    return lse - l[c];
}

// One thread block (256 threads) per 16^3 octree block. 16 voxels/thread.
__global__ __launch_bounds__(256, 4) void level0_kernel(
    const int* __restrict__ gt,        // [256^3], values +-1, x-major (x,y,z)
    const float* __restrict__ logits,  // [4096, 2, 4096]
    float* __restrict__ partial,       // [4096] per-block mean NLL
    int* __restrict__ ones_count)      // [4096] per-block popcount of gt01
{
    const int blk = blockIdx.x;              // (bx*16 + by)*16 + bz
    const int tid = threadIdx.x;
    const int bx = blk >> 8;
    const int by = (blk >> 4) & 15;
    const int bz = blk & 15;

    const float* lg0 = logits + (size_t)blk * 8192;
    const float* lg1 = lg0 + 4096;

    // base global gt index of this block's corner: x*65536 + y*256 + z
    const int gbase = (bx << 20) + (by << 12) + (bz << 4);

    // ---- issue all 12 loads up front (independent, 16 B each) ----
    int4   g[4];
    float4 a[4];
    float4 b[4];
#pragma unroll
    for (int i = 0; i < 4; ++i) {
        const int v  = i * 1024 + (tid << 2);   // voxel idx (ix*16+iy)*16+iz
        const int ix = v >> 8;
        const int iy = (v >> 4) & 15;
        const int iz = v & 15;
        g[i] = *reinterpret_cast<const int4*>(gt + gbase + (ix << 16) + (iy << 8) + iz);
    }
#pragma unroll
    for (int i = 0; i < 4; ++i) {
        const int v = i * 1024 + (tid << 2);
        a[i] = *reinterpret_cast<const float4*>(lg0 + v);
        b[i] = *reinterpret_cast<const float4*>(lg1 + v);
    }

    // ---- per-voxel 2-class CE: target=1 -> softplus(l0-l1); 0 -> softplus(l1-l0)
    float lsum = 0.f;
    int   ones = 0;
#pragma unroll
    for (int i = 0; i < 4; ++i) {
        const float dx = a[i].x - b[i].x;
        const float dy = a[i].y - b[i].y;
        const float dz = a[i].z - b[i].z;
        const float dw = a[i].w - b[i].w;
        const int t0 = g[i].x > 0, t1 = g[i].y > 0, t2 = g[i].z > 0, t3 = g[i].w > 0;
        ones += t0 + t1 + t2 + t3;
        lsum += softplus(t0 ? dx : -dx)
              + softplus(t1 ? dy : -dy)
              + softplus(t2 ? dz : -dz)
              + softplus(t3 ? dw : -dw);
    }

    // ---- wave reduce (4 waves), then cross-wave via LDS ----
#pragma unroll
    for (int s = 32; s > 0; s >>= 1) {
        lsum += __shfl_down(lsum, s, 64);
        ones += __shfl_down(ones, s, 64);
    }
    __shared__ float sf[4];
    __shared__ int   si[4];
    const int wave = tid >> 6;
    if ((tid & 63) == 0) { sf[wave] = lsum; si[wave] = ones; }
    __syncthreads();
    if (tid == 0) {
        const float fs = sf[0] + sf[1] + sf[2] + sf[3];
        const int   is = si[0] + si[1] + si[2] + si[3];
        partial[blk] = fs * (1.0f / 4096.0f);   // mean over 16^3 voxels
        ones_count[blk] = is;
    }
}

// Single block, 512 threads: reduce level-0 partials, hierarchical popcount
// aggregation, 3-class CE for levels 1..4, write final out[0].
__global__ __launch_bounds__(512) void levels_kernel(
    const float* __restrict__ partial, // [4096]
    const int* __restrict__ cnt0,      // [4096] ordered (bx*16+by)*16+bz
    const float* __restrict__ l1,      // [512,3]
    const float* __restrict__ l2,      // [64,3]
    const float* __restrict__ l3,      // [8,3]
    const float* __restrict__ l4,      // [1,3]
    float* __restrict__ out)
{
    __shared__ int   s1[512];
    __shared__ int   s2[64];
    __shared__ int   s3[8];
    __shared__ float red[512];
    const int tid = threadIdx.x;
    float contrib = 0.f;

    // level-0 partial losses: 8 floats per thread
    {
        const float4 p0 = *reinterpret_cast<const float4*>(partial + tid * 8);
        const float4 p1 = *reinterpret_cast<const float4*>(partial + tid * 8 + 4);
        contrib += (p0.x + p0.y + p0.z + p0.w) + (p1.x + p1.y + p1.z + p1.w);
    }

    // level 1: 8^3 blocks, each aggregates 2^3 level-0 blocks (16^3 grid)
    {
        const int X = tid >> 6, Y = (tid >> 3) & 7, Z = tid & 7;
        int s = 0;
#pragma unroll
        for (int dx = 0; dx < 2; ++dx)
#pragma unroll
            for (int dy = 0; dy < 2; ++dy)
#pragma unroll
                for (int dz = 0; dz < 2; ++dz)
                    s += cnt0[((X * 2 + dx) * 16 + (Y * 2 + dy)) * 16 + (Z * 2 + dz)];
        s1[tid] = s;
        const int tot = 8 * 4096;
        const int c = (s == 0) ? 0 : ((s == tot) ? 1 : 2);
        contrib += nll3(l1 + tid * 3, c) * 32768.0f;      // 32^3
    }
    __syncthreads();
    // level 2: 4^3 blocks from 8^3 grid
    if (tid < 64) {
        const int X = tid >> 4, Y = (tid >> 2) & 3, Z = tid & 3;
        int s = 0;
#pragma unroll
        for (int dx = 0; dx < 2; ++dx)
#pragma unroll
            for (int dy = 0; dy < 2; ++dy)
#pragma unroll
                for (int dz = 0; dz < 2; ++dz)
                    s += s1[((X * 2 + dx) * 8 + (Y * 2 + dy)) * 8 + (Z * 2 + dz)];
        s2[tid] = s;
        const int tot = 64 * 4096;
        const int c = (s == 0) ? 0 : ((s == tot) ? 1 : 2);
        contrib += nll3(l2 + tid * 3, c) * 262144.0f;     // 64^3
    }
    __syncthreads();
    // level 3: 2^3 blocks from 4^3 grid
    if (tid < 8) {
        const int X = tid >> 2, Y = (tid >> 1) & 1, Z = tid & 1;
        int s = 0;
#pragma unroll
        for (int dx = 0; dx < 2; ++dx)
#pragma unroll
            for (int dy = 0; dy < 2; ++dy)
#pragma unroll
                for (int dz = 0; dz < 2; ++dz)
                    s += s2[((X * 2 + dx) * 4 + (Y * 2 + dy)) * 4 + (Z * 2 + dz)];
        s3[tid] = s;
        const int tot = 512 * 4096;
        const int c = (s == 0) ? 0 : ((s == tot) ? 1 : 2);
        contrib += nll3(l3 + tid * 3, c) * 2097152.0f;    // 128^3
    }
    __syncthreads();
    // level 4: 1 block = everything
    if (tid == 0) {
        int s = 0;
#pragma unroll
        for (int i = 0; i < 8; ++i) s += s3[i];
        const int tot = 4096 * 4096;
        const int c = (s == 0) ? 0 : ((s == tot) ? 1 : 2);
        contrib += nll3(l4, c) * 16777216.0f;             // 256^3
    }

    red[tid] = contrib;
    __syncthreads();
#pragma unroll
    for (int s = 256; s > 0; s >>= 1) {
        if (tid < s) red[tid] += red[tid + s];
        __syncthreads();
    }
    if (tid == 0) out[0] = red[0];
}

extern "C" void kernel_launch(void* const* d_in, const int* in_sizes, int n_in,
                              void* d_out, int out_size, void* d_ws, size_t ws_size,
                              hipStream_t stream) {
    const int*   gt    = (const int*)d_in[0];
    const float* dense = (const float*)d_in[1];
    const float* l1    = (const float*)d_in[2];
    const float* l2    = (const float*)d_in[3];
    const float* l3    = (const float*)d_in[4];
    const float* l4    = (const float*)d_in[5];
    float* out = (float*)d_out;

    float* partial = (float*)d_ws;            // 4096 floats
    int*   cnt     = (int*)(partial + 4096);  // 4096 ints

    level0_kernel<<<4096, 256, 0, stream>>>(gt, dense, partial, cnt);
    levels_kernel<<<1, 512, 0, stream>>>(partial, cnt, l1, l2, l3, l4, out);
}

// Round 2
// 246.469 us; speedup vs baseline: 1.0018x; 1.0018x over previous
//
#include <hip/hip_runtime.h>

// Octree cross-entropy loss.
// D=256, BS=16 -> 4096 level-0 blocks of 16^3 voxels.
// Level 0: per-voxel 2-class CE, mean over block, summed over blocks.
// Levels 1..4 (b = 32,64,128,256): 3-class CE (pure0/pure1/mixed) * b^3,
// class derived from per-16^3-block popcounts of gt01 aggregated upward.
//
// R4 -> R5 changes:
//  - level0: logits staged HBM->LDS via __builtin_amdgcn_global_load_lds
//    (width 16). R3/R4 both plateaued at ~1650 GB/s (20% peak) because the
//    register allocator (16 / 28 VGPRs) re-serialized every register-resident
//    prefetch: ~1-3 outstanding VMEM/wave regardless of source structure.
//    global_load_lds needs NO destination VGPRs: each wave issues its 8 KB
//    of staging back-to-back, 32 KB per block in flight, 4 blocks/CU
//    (LDS 32 KB/block) -> ~100+ KB in flight per CU vs ~22 KB needed for
//    6.3 TB/s. Readback is linear ds_read_b128 (conflict-free).

__device__ __forceinline__ float softplus(float x) {
    // log(1 + e^x), stable
    return fmaxf(x, 0.f) + __logf(1.f + __expf(-fabsf(x)));
}

__device__ __forceinline__ float nll3(const float* __restrict__ l, int c) {
    float a = l[0], b = l[1], d = l[2];
    float m = fmaxf(fmaxf(a, b), d);
    float lse = m + __logf(__expf(a - m) + __expf(b - m) + __expf(d - m));
    return lse - l[c];
}

// HBM -> LDS direct DMA, 16 B per lane. Dest is wave-uniform base + lane*16.
#define GLOAD_LDS16(gsrc, ldst)                                                \
    __builtin_amdgcn_global_load_lds(                                          \
        (const __attribute__((address_space(1))) void*)(gsrc),                 \
        (__attribute__((address_space(3))) void*)(ldst), 16, 0, 0)

// One thread block (256 threads) per 16^3 octree block. 16 voxels/thread.
__global__ __launch_bounds__(256, 4) void level0_kernel(
    const int* __restrict__ gt,        // [256^3], values +-1, x-major (x,y,z)
    const float* __restrict__ logits,  // [4096, 2, 4096]
    float* __restrict__ partial,       // [4096] per-block mean NLL
    int* __restrict__ ones_count)      // [4096] per-block popcount of gt01
{
    __shared__ float lbuf[8192];       // [2][4096]: class-0 plane then class-1
    __shared__ float sf[4];
    __shared__ int   si[4];

    const int blk  = blockIdx.x;       // (bx*16 + by)*16 + bz
    const int tid  = threadIdx.x;
    const int lane = tid & 63;
    const int wave = tid >> 6;
    const int bx = blk >> 8;
    const int by = (blk >> 4) & 15;
    const int bz = blk & 15;

    // ---- stage all 32 KB of this block's logits into LDS (no dest VGPRs) ----
    // chunk c (0..31) = floats [c*256, c*256+256) of the 8192-float tile;
    // wave w issues chunks w*8 .. w*8+7 back-to-back. Lane l covers floats
    // c*256 + l*4 .. +3 on both the global and LDS side (linear, coalesced).
    {
        const float* src = logits + (size_t)blk * 8192;
#pragma unroll
        for (int i = 0; i < 8; ++i) {
            const int c = wave * 8 + i;
            GLOAD_LDS16(src + c * 256 + lane * 4, lbuf + c * 256);
        }
    }

    // ---- gt: 4 independent int4 loads per thread (L2/L3-served) ----
    const int gbase = (bx << 20) + (by << 12) + (bz << 4); // x*65536+y*256+z
    int4 g[4];
#pragma unroll
    for (int i = 0; i < 4; ++i) {
        const int v  = i * 1024 + (tid << 2);   // voxel idx (ix*16+iy)*16+iz
        const int ix = v >> 8;
        const int iy = (v >> 4) & 15;
        const int iz = v & 15;
        g[i] = *reinterpret_cast<const int4*>(gt + gbase + (ix << 16) + (iy << 8) + iz);
    }

    __syncthreads();   // drains vmcnt(0): LDS tile ready, g[] ready

    // ---- per-voxel 2-class CE from LDS: tgt=1 -> softplus(l0-l1) etc. ----
    float lsum = 0.f;
    int   ones = 0;
#pragma unroll
    for (int i = 0; i < 4; ++i) {
        const int v = i * 1024 + (tid << 2);
        const float4 a = *reinterpret_cast<const float4*>(lbuf + v);
        const float4 b = *reinterpret_cast<const float4*>(lbuf + 4096 + v);
        const float dx = a.x - b.x;
        const float dy = a.y - b.y;
        const float dz = a.z - b.z;
        const float dw = a.w - b.w;
        const int t0 = g[i].x > 0, t1 = g[i].y > 0, t2 = g[i].z > 0, t3 = g[i].w > 0;
        ones += t0 + t1 + t2 + t3;
        lsum += softplus(t0 ? dx : -dx)
              + softplus(t1 ? dy : -dy)
              + softplus(t2 ? dz : -dz)
              + softplus(t3 ? dw : -dw);
    }

    // ---- wave reduce (4 waves), then cross-wave via LDS ----
#pragma unroll
    for (int s = 32; s > 0; s >>= 1) {
        lsum += __shfl_down(lsum, s, 64);
        ones += __shfl_down(ones, s, 64);
    }
    if ((tid & 63) == 0) { sf[wave] = lsum; si[wave] = ones; }
    __syncthreads();
    if (tid == 0) {
        const float fs = sf[0] + sf[1] + sf[2] + sf[3];
        const int   is = si[0] + si[1] + si[2] + si[3];
        partial[blk] = fs * (1.0f / 4096.0f);   // mean over 16^3 voxels
        ones_count[blk] = is;
    }
}

// Single block, 512 threads: reduce level-0 partials, hierarchical popcount
// aggregation, 3-class CE for levels 1..4, write final out[0].
__global__ __launch_bounds__(512) void levels_kernel(
    const float* __restrict__ partial, // [4096]
    const int* __restrict__ cnt0,      // [4096] ordered (bx*16+by)*16+bz
    const float* __restrict__ l1,      // [512,3]
    const float* __restrict__ l2,      // [64,3]
    const float* __restrict__ l3,      // [8,3]
    const float* __restrict__ l4,      // [1,3]
    float* __restrict__ out)
{
    __shared__ int   s1[512];
    __shared__ int   s2[64];
    __shared__ int   s3[8];
    __shared__ float red[512];
    const int tid = threadIdx.x;
    float contrib = 0.f;

    // level-0 partial losses: 8 floats per thread
    {
        const float4 p0 = *reinterpret_cast<const float4*>(partial + tid * 8);
        const float4 p1 = *reinterpret_cast<const float4*>(partial + tid * 8 + 4);
        contrib += (p0.x + p0.y + p0.z + p0.w) + (p1.x + p1.y + p1.z + p1.w);
    }

    // level 1: 8^3 blocks, each aggregates 2^3 level-0 blocks (16^3 grid)
    {
        const int X = tid >> 6, Y = (tid >> 3) & 7, Z = tid & 7;
        int s = 0;
#pragma unroll
        for (int dx = 0; dx < 2; ++dx)
#pragma unroll
            for (int dy = 0; dy < 2; ++dy)
#pragma unroll
                for (int dz = 0; dz < 2; ++dz)
                    s += cnt0[((X * 2 + dx) * 16 + (Y * 2 + dy)) * 16 + (Z * 2 + dz)];
        s1[tid] = s;
        const int tot = 8 * 4096;
        const int c = (s == 0) ? 0 : ((s == tot) ? 1 : 2);
        contrib += nll3(l1 + tid * 3, c) * 32768.0f;      // 32^3
    }
    __syncthreads();
    // level 2: 4^3 blocks from 8^3 grid
    if (tid < 64) {
        const int X = tid >> 4, Y = (tid >> 2) & 3, Z = tid & 3;
        int s = 0;
#pragma unroll
        for (int dx = 0; dx < 2; ++dx)
#pragma unroll
            for (int dy = 0; dy < 2; ++dy)
#pragma unroll
                for (int dz = 0; dz < 2; ++dz)
                    s += s1[((X * 2 + dx) * 8 + (Y * 2 + dy)) * 8 + (Z * 2 + dz)];
        s2[tid] = s;
        const int tot = 64 * 4096;
        const int c = (s == 0) ? 0 : ((s == tot) ? 1 : 2);
        contrib += nll3(l2 + tid * 3, c) * 262144.0f;     // 64^3
    }
    __syncthreads();
    // level 3: 2^3 blocks from 4^3 grid
    if (tid < 8) {
        const int X = tid >> 2, Y = (tid >> 1) & 1, Z = tid & 1;
        int s = 0;
#pragma unroll
        for (int dx = 0; dx < 2; ++dx)
#pragma unroll
            for (int dy = 0; dy < 2; ++dy)
#pragma unroll
                for (int dz = 0; dz < 2; ++dz)
                    s += s2[((X * 2 + dx) * 4 + (Y * 2 + dy)) * 4 + (Z * 2 + dz)];
        s3[tid] = s;
        const int tot = 512 * 4096;
        const int c = (s == 0) ? 0 : ((s == tot) ? 1 : 2);
        contrib += nll3(l3 + tid * 3, c) * 2097152.0f;    // 128^3
    }
    __syncthreads();
    // level 4: 1 block = everything
    if (tid == 0) {
        int s = 0;
#pragma unroll
        for (int i = 0; i < 8; ++i) s += s3[i];
        const int tot = 4096 * 4096;
        const int c = (s == 0) ? 0 : ((s == tot) ? 1 : 2);
        contrib += nll3(l4, c) * 16777216.0f;             // 256^3
    }

    red[tid] = contrib;
    __syncthreads();
#pragma unroll
    for (int s = 256; s > 0; s >>= 1) {
        if (tid < s) red[tid] += red[tid + s];
        __syncthreads();
    }
    if (tid == 0) out[0] = red[0];
}

extern "C" void kernel_launch(void* const* d_in, const int* in_sizes, int n_in,
                              void* d_out, int out_size, void* d_ws, size_t ws_size,
                              hipStream_t stream) {
    const int*   gt    = (const int*)d_in[0];
    const float* dense = (const float*)d_in[1];
    const float* l1    = (const float*)d_in[2];
    const float* l2    = (const float*)d_in[3];
    const float* l3    = (const float*)d_in[4];
    const float* l4    = (const float*)d_in[5];
    float* out = (float*)d_out;

    float* partial = (float*)d_ws;            // 4096 floats
    int*   cnt     = (int*)(partial + 4096);  // 4096 ints

    level0_kernel<<<4096, 256, 0, stream>>>(gt, dense, partial, cnt);
    levels_kernel<<<1, 512, 0, stream>>>(partial, cnt, l1, l2, l3, l4, out);
}